// Round 3
// baseline (47.752 us; speedup 1.0000x reference)
//
#include <hip/hip_runtime.h>

// PatchManifold: bilinear 10x downsample (align_corners=False, scale 10 ->
// frac == 0.5 exactly -> each resized pixel = mean of a 2x2 input block at
// rows 10i+4,10i+5 / cols 10j+4,10j+5), then 16x16 pairwise patch affinity
// mean_d(exp(-(Pa-Pb)^2)), diag == 1, zero the 2 smallest entries per row
// (stable first-index tie-break, matching jnp.argsort take-k semantics).
//
// Input : d_in[0] = targets f32 [8,3,2560,2560]
// Output: d_out   = f32 [16,16]
// ws    : 64 shadows x 128 f64 slots = 64 KiB of pair accumulators
//
// Structure (3 dispatches):
//   memset(64KB) ; pm_fused <<<1536,64>>> ; pm_finish <<<1,256>>>
// pm_fused: thread = one column d of P[16][98304]; 32 strided float2 loads
// (ILP-32 hides HBM latency; 6 blocks/CU exactly), 120 __expf, then two
// 60-pair passes of a 6-stage transposed butterfly (63 shfl each, v[64]
// keeps VGPRs ~100); lane ends owning slot bitrev6(lane), one f64 global
// atomic per pass into blk&63 shadow (24-deep chains).

#define W_IN 2560
#define IMG_STRIDE (2560 * 2560)
#define D_TOTAL 98304.0
#define NSHADOW 64
#define SLOT_STRIDE 128
#define SHADOW_BYTES (NSHADOW * SLOT_STRIDE * 8)   // 64 KiB

__global__ __launch_bounds__(64) void pm_fused(const float* __restrict__ in,
                                               double* __restrict__ acc) {
    const int blk  = blockIdx.x;        // 0..1535 = img(24) * hh(64)
    const int hh   = blk & 63;
    const int img  = blk >> 6;
    const int lane = threadIdx.x;       // == ww, 0..63

    const float* base = in + (size_t)img * IMG_STRIDE + (10 * lane + 4);

    // ---- 32 independent float2 loads (all in flight), then P[16] ----
    float2 t[16], u[16];
#pragma unroll
    for (int n = 0; n < 4; ++n) {
        const float* r0 = base + (size_t)(640 * n + 10 * hh + 4) * W_IN;
#pragma unroll
        for (int m = 0; m < 4; ++m) {
            t[n * 4 + m] = *reinterpret_cast<const float2*>(r0 + 640 * m);
            u[n * 4 + m] = *reinterpret_cast<const float2*>(r0 + 640 * m + W_IN);
        }
    }
    float P[16];
#pragma unroll
    for (int p = 0; p < 16; ++p)
        P[p] = 0.25f * ((t[p].x + t[p].y) + (u[p].x + u[p].y));

    double* shadow = acc + (size_t)(blk & (NSHADOW - 1)) * SLOT_STRIDE;
    const int r = __brev(lane) >> 26;   // 6-bit bit-reverse

    // ---- two passes of 60 pairs; per pass a 6-stage butterfly over v[64] ----
#pragma unroll
    for (int pass = 0; pass < 2; ++pass) {
        float v[64];
        {
            int k = 0;
#pragma unroll
            for (int a = 0; a < 16; ++a)
#pragma unroll
                for (int b = a + 1; b < 16; ++b) {
                    if (k >= pass * 60 && k < pass * 60 + 60) {
                        float df = P[a] - P[b];
                        v[k - pass * 60] = __expf(-df * df);
                    }
                    ++k;
                }
        }
        v[60] = 0.0f; v[61] = 0.0f; v[62] = 0.0f; v[63] = 0.0f;

        // stage K: bit-K lanes swap halves; slot contribution of bit K = 32>>K
        // -> final: lane holds slot bitrev6(lane), fully wave-summed.
#define PM_STAGE(K, H)                                         \
        {                                                      \
            const bool bit = (lane >> (K)) & 1;                \
            _Pragma("unroll")                                  \
            for (int i = 0; i < (H); ++i) {                    \
                float keep = bit ? v[i + (H)] : v[i];          \
                float send = bit ? v[i] : v[i + (H)];          \
                v[i] = keep + __shfl_xor(send, 1 << (K), 64);  \
            }                                                  \
        }
        PM_STAGE(0, 32)
        PM_STAGE(1, 16)
        PM_STAGE(2, 8)
        PM_STAGE(3, 4)
        PM_STAGE(4, 2)
        PM_STAGE(5, 1)
#undef PM_STAGE

        if (r < 60) atomicAdd(&shadow[pass * 64 + r], (double)v[0]);
    }
}

__global__ __launch_bounds__(256) void pm_finish(const double* __restrict__ acc,
                                                 float* __restrict__ out) {
    __shared__ float aff[256];
    const int tid = threadIdx.x;
    const int a = tid >> 4, b = tid & 15;
    if (a < b) {
        int k = 15 * a - (a * (a - 1)) / 2 + (b - a - 1);  // pair index, (a,b>a) order
        int slot = (k < 60) ? k : k + 4;                   // pass1 lives at 64+
        double s = 0.0;
#pragma unroll
        for (int c = 0; c < NSHADOW; ++c) s += acc[c * SLOT_STRIDE + slot];
        float vv = (float)(s * (1.0 / D_TOTAL));
        aff[a * 16 + b] = vv;
        aff[b * 16 + a] = vv;
    } else if (a == b) {
        aff[tid] = 1.0f;               // mean(exp(0)) == 1 exactly
    }
    __syncthreads();
    if (tid < 16) {
        const float* row = &aff[tid * 16];
        // two smallest, stable first-index tie-break (matches jnp.argsort)
        float v1 = 1e30f; int i1 = -1;
        for (int j = 0; j < 16; ++j) {
            float x = row[j];
            if (x < v1) { v1 = x; i1 = j; }
        }
        float v2 = 1e30f; int i2 = -1;
        for (int j = 0; j < 16; ++j) {
            if (j == i1) continue;
            float x = row[j];
            if (x < v2) { v2 = x; i2 = j; }
        }
        for (int j = 0; j < 16; ++j)
            out[tid * 16 + j] = (j == i1 || j == i2) ? 0.0f : row[j];
    }
}

extern "C" void kernel_launch(void* const* d_in, const int* in_sizes, int n_in,
                              void* d_out, int out_size, void* d_ws, size_t ws_size,
                              hipStream_t stream) {
    const float* in = (const float*)d_in[0];
    float* out = (float*)d_out;
    double* acc = (double*)d_ws;

    hipMemsetAsync(d_ws, 0, SHADOW_BYTES, stream);
    pm_fused<<<dim3(1536), dim3(64), 0, stream>>>(in, acc);
    pm_finish<<<dim3(1), dim3(256), 0, stream>>>(acc, out);
}